// Round 4
// baseline (1301.346 us; speedup 1.0000x reference)
//
#include <hip/hip_runtime.h>
#include <math.h>

#define NN 50000
#define NE 800000

typedef float f32x4 __attribute__((ext_vector_type(4)));
typedef short s16x8 __attribute__((ext_vector_type(8)));
typedef unsigned int u32;

__device__ __forceinline__ short f2bf(float f) {
    union { float f; u32 u; } v; v.f = f;
    u32 u = v.u;
    u += 0x7FFF + ((u >> 16) & 1);   // round-to-nearest-even
    return (short)(u >> 16);
}

__device__ __forceinline__ float u2f(u32 u) {
    union { u32 u; float f; } v; v.u = u; return v.f;
}

__device__ __forceinline__ s16x8 cvt8(f32x4 a, f32x4 b) {
    s16x8 r;
    r[0] = f2bf(a[0]); r[1] = f2bf(a[1]); r[2] = f2bf(a[2]); r[3] = f2bf(a[3]);
    r[4] = f2bf(b[0]); r[5] = f2bf(b[1]); r[6] = f2bf(b[2]); r[7] = f2bf(b[3]);
    return r;
}

__device__ __forceinline__ float gelu_exact(float x) {
    return 0.5f * x * (1.0f + erff(x * 0.70710678118654752f));
}

// ---- prep: transpose-convert e_w1 to bf16 [col][k] (w2 now consumed raw f32) ----
__global__ __launch_bounds__(256) void prep_e(
    const float* __restrict__ ew1, short* __restrict__ ew1t)
{
    int idx = blockIdx.x * 256 + threadIdx.x;
    if (idx < 24576) {                       // e_w1 [192][128] -> [128][192]
        int k = idx >> 7, c = idx & 127;
        ew1t[c * 192 + k] = f2bf(ew1[idx]);
    }
}

// ---- edge kernel ----
// GEMM1: MFMA (BYTE-IDENTICAL to round 3: hand-unrolled KSTEPs) + C/D-layout
//        h-write. GEMM2 + epilogue: layout-free VALU (node_valu-certified
//        pattern, lane = output column). This halves the bug suspect space.
__global__ __launch_bounds__(256) void edge_k(
    const float* __restrict__ nf, const int* __restrict__ ei,
    const float* __restrict__ ef,
    const short* __restrict__ w1t, const float* __restrict__ b1,
    const float* __restrict__ w2, const float* __restrict__ b2,
    const float* __restrict__ gamma, const float* __restrict__ beta,
    float* __restrict__ eout, float* __restrict__ agg, float* __restrict__ cnt)
{
    __shared__ short h_lds[128][136];        // +8 pad
    const int tid  = threadIdx.x;
    const int wave = tid >> 6, lane = tid & 63;
    const int lo = lane & 15, hi = lane >> 4;
    const int eb = blockIdx.x * 128 + wave * 32;

    const int ar0 = eb + lo, ar1 = eb + 16 + lo;
    const int s0 = ei[ar0], s1 = ei[ar1];
    const int d0 = ei[NE + ar0], d1 = ei[NE + ar1];

    const float* pS0 = nf + (size_t)s0 * 64;
    const float* pS1 = nf + (size_t)s1 * 64;
    const float* pD0 = nf + (size_t)d0 * 64;
    const float* pD1 = nf + (size_t)d1 * 64;
    const float* pE0 = ef + (size_t)ar0 * 64;
    const float* pE1 = ef + (size_t)ar1 * 64;
    const int o0 = hi * 8, o1 = 32 + hi * 8;

    f32x4 acc[2][8];
#pragma unroll
    for (int i = 0; i < 2; ++i)
#pragma unroll
        for (int j = 0; j < 8; ++j)
#pragma unroll
            for (int q = 0; q < 4; ++q) acc[i][j][q] = 0.0f;

#define KSTEP(PTR0, PTR1, OFF, K0)                                              \
    {                                                                           \
        f32x4 x0l = *(const f32x4*)((PTR0) + (OFF));                            \
        f32x4 x0h = *(const f32x4*)((PTR0) + (OFF) + 4);                        \
        f32x4 x1l = *(const f32x4*)((PTR1) + (OFF));                            \
        f32x4 x1h = *(const f32x4*)((PTR1) + (OFF) + 4);                        \
        s16x8 fa0 = cvt8(x0l, x0h), fa1 = cvt8(x1l, x1h);                       \
        _Pragma("unroll")                                                       \
        for (int ct = 0; ct < 8; ++ct) {                                        \
            s16x8 b = *(const s16x8*)(w1t + (ct * 16 + lo) * 192 + (K0) + hi * 8); \
            acc[0][ct] = __builtin_amdgcn_mfma_f32_16x16x32_bf16(fa0, b, acc[0][ct], 0, 0, 0); \
            acc[1][ct] = __builtin_amdgcn_mfma_f32_16x16x32_bf16(fa1, b, acc[1][ct], 0, 0, 0); \
        }                                                                       \
    }

    KSTEP(pS0, pS1, o0, 0);      // k   0..31 : nf[src] 0..31
    KSTEP(pS0, pS1, o1, 32);     // k  32..63 : nf[src] 32..63
    KSTEP(pD0, pD1, o0, 64);     // k  64..95 : nf[dst] 0..31
    KSTEP(pD0, pD1, o1, 96);     // k  96..127: nf[dst] 32..63
    KSTEP(pE0, pE1, o0, 128);    // k 128..159: ef 0..31
    KSTEP(pE0, pE1, o1, 160);    // k 160..191: ef 32..63
#undef KSTEP

    // bias + exact GELU -> h_lds (bf16), C/D layout: row=(hi*4+r), col=lo-based
#pragma unroll
    for (int ct = 0; ct < 8; ++ct) {
        const int col = ct * 16 + lo;
        const float bb = b1[col];
#pragma unroll
        for (int rt = 0; rt < 2; ++rt)
#pragma unroll
            for (int r = 0; r < 4; ++r) {
                float x = acc[rt][ct][r] + bb;
                h_lds[wave * 32 + rt * 16 + hi * 4 + r][col] = f2bf(gelu_exact(x));
            }
    }
    __syncthreads();

    // ---- GEMM2 + epilogue: pure VALU, lane = output column (0..63) ----
    // pack this lane's w2 column into 64 bf16-pair registers (once per wave)
    u32 w2p[64];
#pragma unroll
    for (int j = 0; j < 64; ++j) {
        u32 a = (u32)(unsigned short)f2bf(w2[(2 * j) * 64 + lane]);
        u32 b = (u32)(unsigned short)f2bf(w2[(2 * j + 1) * 64 + lane]);
        w2p[j] = a | (b << 16);
    }
    const float b2v = b2[lane], gmv = gamma[lane], btv = beta[lane];

    for (int e = 0; e < 32; ++e) {
        const int er   = wave * 32 + e;              // block-local row
        const int erow = blockIdx.x * 128 + er;      // global edge row
        float oa = b2v, ob = 0.0f;
#pragma unroll
        for (int j = 0; j < 64; ++j) {
            const u32 hu = *(const u32*)&h_lds[er][2 * j];   // broadcast read
            oa += u2f(hu << 16)          * u2f(w2p[j] << 16);
            ob += u2f(hu & 0xFFFF0000u)  * u2f(w2p[j] & 0xFFFF0000u);
        }
        float o = oa + ob + ef[(size_t)erow * 64 + lane];     // + residual
        float s = o, s2 = o * o;
#pragma unroll
        for (int m = 1; m < 64; m <<= 1) { s += __shfl_xor(s, m); s2 += __shfl_xor(s2, m); }
        const float mean = s * 0.015625f;
        const float var  = s2 * 0.015625f - mean * mean;
        const float rs   = rsqrtf(var + 1e-5f);
        const float out  = (o - mean) * rs * gmv + btv;
        eout[(size_t)erow * 64 + lane] = out;
        const int dn = ei[NE + erow];
        atomicAdd(&agg[(size_t)dn * 64 + lane], out);
        if (lane == 0) atomicAdd(&cnt[dn], 1.0f);
    }
}

// ---- node kernel: simple per-wave f32 VALU (PASSED rounds 2 & 3 — unchanged) ----
__global__ __launch_bounds__(256) void node_valu(
    const float* __restrict__ nf,
    const float* __restrict__ w1, const float* __restrict__ b1,   // [128][128], [128]
    const float* __restrict__ w2, const float* __restrict__ b2,   // [128][64],  [64]
    const float* __restrict__ gamma, const float* __restrict__ beta,
    const float* __restrict__ agg, const float* __restrict__ cnt,
    float* __restrict__ nout)
{
    __shared__ float xs[4][128];
    __shared__ float hs[4][128];
    const int wave = threadIdx.x >> 6, lane = threadIdx.x & 63;
    const int n = blockIdx.x * 4 + wave;         // grid covers exactly NN
    if (n >= NN) return;                          // whole-wave exit; no __syncthreads here

    const float ic = 1.0f / fmaxf(cnt[n], 1.0f);
    xs[wave][lane]      = nf[(size_t)n * 64 + lane];
    xs[wave][64 + lane] = agg[(size_t)n * 64 + lane] * ic;

    float a0 = b1[lane], a1 = b1[64 + lane];
#pragma unroll 8
    for (int k = 0; k < 128; ++k) {
        const float xv = xs[wave][k];            // LDS broadcast
        a0 += xv * w1[k * 128 + lane];
        a1 += xv * w1[k * 128 + 64 + lane];
    }
    hs[wave][lane]      = gelu_exact(a0);
    hs[wave][64 + lane] = gelu_exact(a1);

    float o = b2[lane];
#pragma unroll 8
    for (int k = 0; k < 128; ++k)
        o += hs[wave][k] * w2[k * 64 + lane];
    o += nf[(size_t)n * 64 + lane];              // residual

    float s = o, s2 = o * o;
#pragma unroll
    for (int m = 1; m < 64; m <<= 1) { s += __shfl_xor(s, m); s2 += __shfl_xor(s2, m); }
    const float mean = s * 0.015625f;
    const float var  = s2 * 0.015625f - mean * mean;
    const float rs   = rsqrtf(var + 1e-5f);
    nout[(size_t)n * 64 + lane] = (o - mean) * rs * gamma[lane] + beta[lane];
}

extern "C" void kernel_launch(void* const* d_in, const int* in_sizes, int n_in,
                              void* d_out, int out_size, void* d_ws, size_t ws_size,
                              hipStream_t stream)
{
    const float* nf  = (const float*)d_in[0];
    const int*   ei  = (const int*)d_in[1];
    const float* ef  = (const float*)d_in[2];
    const float* ew1 = (const float*)d_in[3];
    const float* eb1 = (const float*)d_in[4];
    const float* ew2 = (const float*)d_in[5];
    const float* eb2 = (const float*)d_in[6];
    const float* nw1 = (const float*)d_in[7];
    const float* nb1 = (const float*)d_in[8];
    const float* nw2 = (const float*)d_in[9];
    const float* nb2 = (const float*)d_in[10];
    const float* eg  = (const float*)d_in[11];
    const float* ebt = (const float*)d_in[12];
    const float* ng  = (const float*)d_in[13];
    const float* nbt = (const float*)d_in[14];

    float* node_out = (float*)d_out;
    float* edge_out = node_out + (size_t)NN * 64;
    char*  ws   = (char*)d_ws;
    float* cnt  = (float*)(ws);             // 50000*4 = 200000 B
    short* ew1t = (short*)(ws + 200704);    // 128*192*2 = 49152 B
    float* agg  = node_out;                 // reuse node_out region as agg accumulator

    hipMemsetAsync(agg, 0, (size_t)NN * 64 * 4, stream);
    hipMemsetAsync(cnt, 0, (size_t)NN * 4, stream);
    prep_e<<<96, 256, 0, stream>>>(ew1, ew1t);
    edge_k<<<NE / 128, 256, 0, stream>>>(nf, ei, ef, ew1t, eb1, ew2, eb2, eg, ebt,
                                         edge_out, agg, cnt);
    node_valu<<<NN / 4, 256, 0, stream>>>(nf, nw1, nb1, nw2, nb2, ng, nbt,
                                          agg, cnt, node_out);
}

// Round 5
// 668.799 us; speedup vs baseline: 1.9458x; 1.9458x over previous
//
#include <hip/hip_runtime.h>
#include <math.h>

#define NN 50000
#define NE 800000

typedef float f32x4 __attribute__((ext_vector_type(4)));
typedef short s16x8 __attribute__((ext_vector_type(8)));
typedef unsigned int u32;

__device__ __forceinline__ short f2bf(float f) {
    union { float f; u32 u; } v; v.f = f;
    u32 u = v.u;
    u += 0x7FFF + ((u >> 16) & 1);   // round-to-nearest-even
    return (short)(u >> 16);
}

__device__ __forceinline__ s16x8 cvt8(f32x4 a, f32x4 b) {
    s16x8 r;
    r[0] = f2bf(a[0]); r[1] = f2bf(a[1]); r[2] = f2bf(a[2]); r[3] = f2bf(a[3]);
    r[4] = f2bf(b[0]); r[5] = f2bf(b[1]); r[6] = f2bf(b[2]); r[7] = f2bf(b[3]);
    return r;
}

__device__ __forceinline__ float gelu_exact(float x) {
    return 0.5f * x * (1.0f + erff(x * 0.70710678118654752f));
}

// ---- prep: transpose-convert edge weights to bf16 [col][k] ----
__global__ __launch_bounds__(256) void prep_e(
    const float* __restrict__ ew1, const float* __restrict__ ew2,
    short* __restrict__ ew1t, short* __restrict__ ew2t)
{
    int idx = blockIdx.x * 256 + threadIdx.x;
    if (idx < 24576) {                       // e_w1 [192][128] -> [128][192]
        int k = idx >> 7, c = idx & 127;
        ew1t[c * 192 + k] = f2bf(ew1[idx]);
    } else if (idx < 32768) {                // e_w2 [128][64] -> [64][128]
        int i = idx - 24576; int k = i >> 6, c = i & 63;
        ew2t[c * 128 + k] = f2bf(ew2[i]);
    }
}

// ---- edge kernel ----
// GEMM1: certified MFMA (hand-unrolled KSTEPs) + certified C/D h-write.
// GEMM2: MFMA with the SAME (certified) A/B/C-D mappings; result goes
//        through LDS (aliasing h_lds, barrier-separated) into the
//        certified lane=col epilogue.
__global__ __launch_bounds__(256) void edge_k(
    const float* __restrict__ nf, const int* __restrict__ ei,
    const float* __restrict__ ef,
    const short* __restrict__ w1t, const float* __restrict__ b1,
    const short* __restrict__ w2t, const float* __restrict__ b2,
    const float* __restrict__ gamma, const float* __restrict__ beta,
    float* __restrict__ eout, float* __restrict__ agg, float* __restrict__ cnt)
{
    __shared__ short h_lds[128][136];        // 34816 B; aliased as float[128][68] later
    const int tid  = threadIdx.x;
    const int wave = tid >> 6, lane = tid & 63;
    const int lo = lane & 15, hi = lane >> 4;
    const int eb = blockIdx.x * 128 + wave * 32;

    const int ar0 = eb + lo, ar1 = eb + 16 + lo;
    const int s0 = ei[ar0], s1 = ei[ar1];
    const int d0 = ei[NE + ar0], d1 = ei[NE + ar1];

    const float* pS0 = nf + (size_t)s0 * 64;
    const float* pS1 = nf + (size_t)s1 * 64;
    const float* pD0 = nf + (size_t)d0 * 64;
    const float* pD1 = nf + (size_t)d1 * 64;
    const float* pE0 = ef + (size_t)ar0 * 64;
    const float* pE1 = ef + (size_t)ar1 * 64;
    const int o0 = hi * 8, o1 = 32 + hi * 8;

    f32x4 acc[2][8];
#pragma unroll
    for (int i = 0; i < 2; ++i)
#pragma unroll
        for (int j = 0; j < 8; ++j)
#pragma unroll
            for (int q = 0; q < 4; ++q) acc[i][j][q] = 0.0f;

#define KSTEP(PTR0, PTR1, OFF, K0)                                              \
    {                                                                           \
        f32x4 x0l = *(const f32x4*)((PTR0) + (OFF));                            \
        f32x4 x0h = *(const f32x4*)((PTR0) + (OFF) + 4);                        \
        f32x4 x1l = *(const f32x4*)((PTR1) + (OFF));                            \
        f32x4 x1h = *(const f32x4*)((PTR1) + (OFF) + 4);                        \
        s16x8 fa0 = cvt8(x0l, x0h), fa1 = cvt8(x1l, x1h);                       \
        _Pragma("unroll")                                                       \
        for (int ct = 0; ct < 8; ++ct) {                                        \
            s16x8 b = *(const s16x8*)(w1t + (ct * 16 + lo) * 192 + (K0) + hi * 8); \
            acc[0][ct] = __builtin_amdgcn_mfma_f32_16x16x32_bf16(fa0, b, acc[0][ct], 0, 0, 0); \
            acc[1][ct] = __builtin_amdgcn_mfma_f32_16x16x32_bf16(fa1, b, acc[1][ct], 0, 0, 0); \
        }                                                                       \
    }

    KSTEP(pS0, pS1, o0, 0);      // k   0..31 : nf[src] 0..31
    KSTEP(pS0, pS1, o1, 32);     // k  32..63 : nf[src] 32..63
    KSTEP(pD0, pD1, o0, 64);     // k  64..95 : nf[dst] 0..31
    KSTEP(pD0, pD1, o1, 96);     // k  96..127: nf[dst] 32..63
    KSTEP(pE0, pE1, o0, 128);    // k 128..159: ef 0..31
    KSTEP(pE0, pE1, o1, 160);    // k 160..191: ef 32..63
#undef KSTEP

    // bias + exact GELU -> h_lds (bf16), certified C/D mapping
#pragma unroll
    for (int ct = 0; ct < 8; ++ct) {
        const int col = ct * 16 + lo;
        const float bb = b1[col];
#pragma unroll
        for (int rt = 0; rt < 2; ++rt)
#pragma unroll
            for (int r = 0; r < 4; ++r) {
                float x = acc[rt][ct][r] + bb;
                h_lds[wave * 32 + rt * 16 + hi * 4 + r][col] = f2bf(gelu_exact(x));
            }
    }
    __syncthreads();

    // ---- GEMM2: [128 x 128] @ [128 x 64], MFMA, same certified mappings ----
    f32x4 acc2[2][4];
#pragma unroll
    for (int i = 0; i < 2; ++i)
#pragma unroll
        for (int j = 0; j < 4; ++j)
#pragma unroll
            for (int q = 0; q < 4; ++q) acc2[i][j][q] = 0.0f;
#pragma unroll
    for (int ks = 0; ks < 4; ++ks) {
        const int k0 = ks * 32 + hi * 8;
        s16x8 a0 = *(const s16x8*)&h_lds[wave * 32 + lo][k0];
        s16x8 a1 = *(const s16x8*)&h_lds[wave * 32 + 16 + lo][k0];
#pragma unroll
        for (int ct = 0; ct < 4; ++ct) {
            s16x8 b = *(const s16x8*)(w2t + (ct * 16 + lo) * 128 + k0);
            acc2[0][ct] = __builtin_amdgcn_mfma_f32_16x16x32_bf16(a0, b, acc2[0][ct], 0, 0, 0);
            acc2[1][ct] = __builtin_amdgcn_mfma_f32_16x16x32_bf16(a1, b, acc2[1][ct], 0, 0, 0);
        }
    }
    __syncthreads();                          // all h reads done before aliasing overwrite

    // write update u to LDS with the certified C/D mapping (alias h_lds as f32)
    float (*u_lds)[68] = (float (*)[68])h_lds;   // 128*68*4 = 34816 B, exact alias
#pragma unroll
    for (int ct = 0; ct < 4; ++ct)
#pragma unroll
        for (int rt = 0; rt < 2; ++rt)
#pragma unroll
            for (int r = 0; r < 4; ++r)
                u_lds[wave * 32 + rt * 16 + hi * 4 + r][ct * 16 + lo] = acc2[rt][ct][r];
    __syncthreads();

    // ---- certified epilogue: lane = output column (0..63) ----
    const float b2v = b2[lane], gmv = gamma[lane], btv = beta[lane];
    for (int e = 0; e < 32; ++e) {
        const int er   = wave * 32 + e;              // block-local row
        const int erow = blockIdx.x * 128 + er;      // global edge row
        float o = u_lds[er][lane] + b2v + ef[(size_t)erow * 64 + lane];
        float s = o, s2 = o * o;
#pragma unroll
        for (int m = 1; m < 64; m <<= 1) { s += __shfl_xor(s, m); s2 += __shfl_xor(s2, m); }
        const float mean = s * 0.015625f;
        const float var  = s2 * 0.015625f - mean * mean;
        const float rs   = rsqrtf(var + 1e-5f);
        const float out  = (o - mean) * rs * gmv + btv;
        eout[(size_t)erow * 64 + lane] = out;
        const int dn = ei[NE + erow];
        atomicAdd(&agg[(size_t)dn * 64 + lane], out);
        if (lane == 0) atomicAdd(&cnt[dn], 1.0f);
    }
}

// ---- node kernel: simple per-wave f32 VALU (certified — unchanged) ----
__global__ __launch_bounds__(256) void node_valu(
    const float* __restrict__ nf,
    const float* __restrict__ w1, const float* __restrict__ b1,   // [128][128], [128]
    const float* __restrict__ w2, const float* __restrict__ b2,   // [128][64],  [64]
    const float* __restrict__ gamma, const float* __restrict__ beta,
    const float* __restrict__ agg, const float* __restrict__ cnt,
    float* __restrict__ nout)
{
    __shared__ float xs[4][128];
    __shared__ float hs[4][128];
    const int wave = threadIdx.x >> 6, lane = threadIdx.x & 63;
    const int n = blockIdx.x * 4 + wave;         // grid covers exactly NN
    if (n >= NN) return;                          // whole-wave exit; no __syncthreads here

    const float ic = 1.0f / fmaxf(cnt[n], 1.0f);
    xs[wave][lane]      = nf[(size_t)n * 64 + lane];
    xs[wave][64 + lane] = agg[(size_t)n * 64 + lane] * ic;

    float a0 = b1[lane], a1 = b1[64 + lane];
#pragma unroll 8
    for (int k = 0; k < 128; ++k) {
        const float xv = xs[wave][k];            // LDS broadcast
        a0 += xv * w1[k * 128 + lane];
        a1 += xv * w1[k * 128 + 64 + lane];
    }
    hs[wave][lane]      = gelu_exact(a0);
    hs[wave][64 + lane] = gelu_exact(a1);

    float o = b2[lane];
#pragma unroll 8
    for (int k = 0; k < 128; ++k)
        o += hs[wave][k] * w2[k * 64 + lane];
    o += nf[(size_t)n * 64 + lane];              // residual

    float s = o, s2 = o * o;
#pragma unroll
    for (int m = 1; m < 64; m <<= 1) { s += __shfl_xor(s, m); s2 += __shfl_xor(s2, m); }
    const float mean = s * 0.015625f;
    const float var  = s2 * 0.015625f - mean * mean;
    const float rs   = rsqrtf(var + 1e-5f);
    nout[(size_t)n * 64 + lane] = (o - mean) * rs * gamma[lane] + beta[lane];
}

extern "C" void kernel_launch(void* const* d_in, const int* in_sizes, int n_in,
                              void* d_out, int out_size, void* d_ws, size_t ws_size,
                              hipStream_t stream)
{
    const float* nf  = (const float*)d_in[0];
    const int*   ei  = (const int*)d_in[1];
    const float* ef  = (const float*)d_in[2];
    const float* ew1 = (const float*)d_in[3];
    const float* eb1 = (const float*)d_in[4];
    const float* ew2 = (const float*)d_in[5];
    const float* eb2 = (const float*)d_in[6];
    const float* nw1 = (const float*)d_in[7];
    const float* nb1 = (const float*)d_in[8];
    const float* nw2 = (const float*)d_in[9];
    const float* nb2 = (const float*)d_in[10];
    const float* eg  = (const float*)d_in[11];
    const float* ebt = (const float*)d_in[12];
    const float* ng  = (const float*)d_in[13];
    const float* nbt = (const float*)d_in[14];

    float* node_out = (float*)d_out;
    float* edge_out = node_out + (size_t)NN * 64;
    char*  ws   = (char*)d_ws;
    float* cnt  = (float*)(ws);             // 50000*4 = 200000 B
    short* ew1t = (short*)(ws + 200704);    // 128*192*2 = 49152 B
    short* ew2t = (short*)(ws + 249856);    // 64*128*2  = 16384 B
    float* agg  = node_out;                 // reuse node_out region as agg accumulator

    hipMemsetAsync(agg, 0, (size_t)NN * 64 * 4, stream);
    hipMemsetAsync(cnt, 0, (size_t)NN * 4, stream);
    prep_e<<<128, 256, 0, stream>>>(ew1, ew2, ew1t, ew2t);
    edge_k<<<NE / 128, 256, 0, stream>>>(nf, ei, ef, ew1t, eb1, ew2t, eb2, eg, ebt,
                                         edge_out, agg, cnt);
    node_valu<<<NN / 4, 256, 0, stream>>>(nf, nw1, nb1, nw2, nb2, ng, nbt,
                                          agg, cnt, node_out);
}

// Round 6
// 668.414 us; speedup vs baseline: 1.9469x; 1.0006x over previous
//
#include <hip/hip_runtime.h>
#include <math.h>

#define NN 50000
#define NE 800000

typedef float f32x4 __attribute__((ext_vector_type(4)));
typedef short s16x8 __attribute__((ext_vector_type(8)));
typedef unsigned int u32;

__device__ __forceinline__ short f2bf(float f) {
    union { float f; u32 u; } v; v.f = f;
    u32 u = v.u;
    u += 0x7FFF + ((u >> 16) & 1);   // round-to-nearest-even
    return (short)(u >> 16);
}

__device__ __forceinline__ s16x8 cvt8(f32x4 a, f32x4 b) {
    s16x8 r;
    r[0] = f2bf(a[0]); r[1] = f2bf(a[1]); r[2] = f2bf(a[2]); r[3] = f2bf(a[3]);
    r[4] = f2bf(b[0]); r[5] = f2bf(b[1]); r[6] = f2bf(b[2]); r[7] = f2bf(b[3]);
    return r;
}

__device__ __forceinline__ float gelu_exact(float x) {
    return 0.5f * x * (1.0f + erff(x * 0.70710678118654752f));
}

// ---- prep: transpose-convert edge weights to bf16 [col][k] ----
__global__ __launch_bounds__(256) void prep_e(
    const float* __restrict__ ew1, const float* __restrict__ ew2,
    short* __restrict__ ew1t, short* __restrict__ ew2t)
{
    int idx = blockIdx.x * 256 + threadIdx.x;
    if (idx < 24576) {                       // e_w1 [192][128] -> [128][192]
        int k = idx >> 7, c = idx & 127;
        ew1t[c * 192 + k] = f2bf(ew1[idx]);
    } else if (idx < 32768) {                // e_w2 [128][64] -> [64][128]
        int i = idx - 24576; int k = i >> 6, c = i & 63;
        ew2t[c * 128 + k] = f2bf(ew2[i]);
    }
}

// ---- edge kernel (certified r5 dataflow) ----
// Round-6 deltas ONLY: (1) h_lds [128][136] -> [128][128] (LDS 34816->32768 B
// => 5 blocks/CU instead of 4; accepts ~16-way conflict on 8 b128 reads/wave,
// ~4us total); (2) epilogue loop unrolled x4 for ILP across shfl trees.
__global__ __launch_bounds__(256) void edge_k(
    const float* __restrict__ nf, const int* __restrict__ ei,
    const float* __restrict__ ef,
    const short* __restrict__ w1t, const float* __restrict__ b1,
    const short* __restrict__ w2t, const float* __restrict__ b2,
    const float* __restrict__ gamma, const float* __restrict__ beta,
    float* __restrict__ eout, float* __restrict__ agg, float* __restrict__ cnt)
{
    __shared__ short h_lds[128][128];        // 32768 B exactly; aliased float[128][64]
    const int tid  = threadIdx.x;
    const int wave = tid >> 6, lane = tid & 63;
    const int lo = lane & 15, hi = lane >> 4;
    const int eb = blockIdx.x * 128 + wave * 32;

    const int ar0 = eb + lo, ar1 = eb + 16 + lo;
    const int s0 = ei[ar0], s1 = ei[ar1];
    const int d0 = ei[NE + ar0], d1 = ei[NE + ar1];

    const float* pS0 = nf + (size_t)s0 * 64;
    const float* pS1 = nf + (size_t)s1 * 64;
    const float* pD0 = nf + (size_t)d0 * 64;
    const float* pD1 = nf + (size_t)d1 * 64;
    const float* pE0 = ef + (size_t)ar0 * 64;
    const float* pE1 = ef + (size_t)ar1 * 64;
    const int o0 = hi * 8, o1 = 32 + hi * 8;

    f32x4 acc[2][8];
#pragma unroll
    for (int i = 0; i < 2; ++i)
#pragma unroll
        for (int j = 0; j < 8; ++j)
#pragma unroll
            for (int q = 0; q < 4; ++q) acc[i][j][q] = 0.0f;

#define KSTEP(PTR0, PTR1, OFF, K0)                                              \
    {                                                                           \
        f32x4 x0l = *(const f32x4*)((PTR0) + (OFF));                            \
        f32x4 x0h = *(const f32x4*)((PTR0) + (OFF) + 4);                        \
        f32x4 x1l = *(const f32x4*)((PTR1) + (OFF));                            \
        f32x4 x1h = *(const f32x4*)((PTR1) + (OFF) + 4);                        \
        s16x8 fa0 = cvt8(x0l, x0h), fa1 = cvt8(x1l, x1h);                       \
        _Pragma("unroll")                                                       \
        for (int ct = 0; ct < 8; ++ct) {                                        \
            s16x8 b = *(const s16x8*)(w1t + (ct * 16 + lo) * 192 + (K0) + hi * 8); \
            acc[0][ct] = __builtin_amdgcn_mfma_f32_16x16x32_bf16(fa0, b, acc[0][ct], 0, 0, 0); \
            acc[1][ct] = __builtin_amdgcn_mfma_f32_16x16x32_bf16(fa1, b, acc[1][ct], 0, 0, 0); \
        }                                                                       \
    }

    KSTEP(pS0, pS1, o0, 0);      // k   0..31 : nf[src] 0..31
    KSTEP(pS0, pS1, o1, 32);     // k  32..63 : nf[src] 32..63
    KSTEP(pD0, pD1, o0, 64);     // k  64..95 : nf[dst] 0..31
    KSTEP(pD0, pD1, o1, 96);     // k  96..127: nf[dst] 32..63
    KSTEP(pE0, pE1, o0, 128);    // k 128..159: ef 0..31
    KSTEP(pE0, pE1, o1, 160);    // k 160..191: ef 32..63
#undef KSTEP

    // bias + exact GELU -> h_lds (bf16), certified C/D mapping
#pragma unroll
    for (int ct = 0; ct < 8; ++ct) {
        const int col = ct * 16 + lo;
        const float bb = b1[col];
#pragma unroll
        for (int rt = 0; rt < 2; ++rt)
#pragma unroll
            for (int r = 0; r < 4; ++r) {
                float x = acc[rt][ct][r] + bb;
                h_lds[wave * 32 + rt * 16 + hi * 4 + r][col] = f2bf(gelu_exact(x));
            }
    }
    __syncthreads();

    // ---- GEMM2: [128 x 128] @ [128 x 64], MFMA, certified mappings ----
    f32x4 acc2[2][4];
#pragma unroll
    for (int i = 0; i < 2; ++i)
#pragma unroll
        for (int j = 0; j < 4; ++j)
#pragma unroll
            for (int q = 0; q < 4; ++q) acc2[i][j][q] = 0.0f;
#pragma unroll
    for (int ks = 0; ks < 4; ++ks) {
        const int k0 = ks * 32 + hi * 8;
        s16x8 a0 = *(const s16x8*)&h_lds[wave * 32 + lo][k0];
        s16x8 a1 = *(const s16x8*)&h_lds[wave * 32 + 16 + lo][k0];
#pragma unroll
        for (int ct = 0; ct < 4; ++ct) {
            s16x8 b = *(const s16x8*)(w2t + (ct * 16 + lo) * 128 + k0);
            acc2[0][ct] = __builtin_amdgcn_mfma_f32_16x16x32_bf16(a0, b, acc2[0][ct], 0, 0, 0);
            acc2[1][ct] = __builtin_amdgcn_mfma_f32_16x16x32_bf16(a1, b, acc2[1][ct], 0, 0, 0);
        }
    }
    __syncthreads();                          // all h reads done before aliasing overwrite

    // write update u to LDS with the certified C/D mapping (alias h_lds as f32)
    float (*u_lds)[64] = (float (*)[64])h_lds;   // 128*64*4 = 32768 B, exact alias
#pragma unroll
    for (int ct = 0; ct < 4; ++ct)
#pragma unroll
        for (int rt = 0; rt < 2; ++rt)
#pragma unroll
            for (int r = 0; r < 4; ++r)
                u_lds[wave * 32 + rt * 16 + hi * 4 + r][ct * 16 + lo] = acc2[rt][ct][r];
    __syncthreads();

    // ---- certified epilogue: lane = output column (0..63), now unrolled x4 ----
    const float b2v = b2[lane], gmv = gamma[lane], btv = beta[lane];
#pragma unroll 4
    for (int e = 0; e < 32; ++e) {
        const int er   = wave * 32 + e;              // block-local row
        const int erow = blockIdx.x * 128 + er;      // global edge row
        float o = u_lds[er][lane] + b2v + ef[(size_t)erow * 64 + lane];
        float s = o, s2 = o * o;
#pragma unroll
        for (int m = 1; m < 64; m <<= 1) { s += __shfl_xor(s, m); s2 += __shfl_xor(s2, m); }
        const float mean = s * 0.015625f;
        const float var  = s2 * 0.015625f - mean * mean;
        const float rs   = rsqrtf(var + 1e-5f);
        const float out  = (o - mean) * rs * gmv + btv;
        eout[(size_t)erow * 64 + lane] = out;
        const int dn = ei[NE + erow];
        atomicAdd(&agg[(size_t)dn * 64 + lane], out);
        if (lane == 0) atomicAdd(&cnt[dn], 1.0f);
    }
}

// ---- node kernel: simple per-wave f32 VALU (certified — unchanged) ----
__global__ __launch_bounds__(256) void node_valu(
    const float* __restrict__ nf,
    const float* __restrict__ w1, const float* __restrict__ b1,   // [128][128], [128]
    const float* __restrict__ w2, const float* __restrict__ b2,   // [128][64],  [64]
    const float* __restrict__ gamma, const float* __restrict__ beta,
    const float* __restrict__ agg, const float* __restrict__ cnt,
    float* __restrict__ nout)
{
    __shared__ float xs[4][128];
    __shared__ float hs[4][128];
    const int wave = threadIdx.x >> 6, lane = threadIdx.x & 63;
    const int n = blockIdx.x * 4 + wave;         // grid covers exactly NN
    if (n >= NN) return;                          // whole-wave exit; no __syncthreads here

    const float ic = 1.0f / fmaxf(cnt[n], 1.0f);
    xs[wave][lane]      = nf[(size_t)n * 64 + lane];
    xs[wave][64 + lane] = agg[(size_t)n * 64 + lane] * ic;

    float a0 = b1[lane], a1 = b1[64 + lane];
#pragma unroll 8
    for (int k = 0; k < 128; ++k) {
        const float xv = xs[wave][k];            // LDS broadcast
        a0 += xv * w1[k * 128 + lane];
        a1 += xv * w1[k * 128 + 64 + lane];
    }
    hs[wave][lane]      = gelu_exact(a0);
    hs[wave][64 + lane] = gelu_exact(a1);

    float o = b2[lane];
#pragma unroll 8
    for (int k = 0; k < 128; ++k)
        o += hs[wave][k] * w2[k * 64 + lane];
    o += nf[(size_t)n * 64 + lane];              // residual

    float s = o, s2 = o * o;
#pragma unroll
    for (int m = 1; m < 64; m <<= 1) { s += __shfl_xor(s, m); s2 += __shfl_xor(s2, m); }
    const float mean = s * 0.015625f;
    const float var  = s2 * 0.015625f - mean * mean;
    const float rs   = rsqrtf(var + 1e-5f);
    nout[(size_t)n * 64 + lane] = (o - mean) * rs * gamma[lane] + beta[lane];
}

extern "C" void kernel_launch(void* const* d_in, const int* in_sizes, int n_in,
                              void* d_out, int out_size, void* d_ws, size_t ws_size,
                              hipStream_t stream)
{
    const float* nf  = (const float*)d_in[0];
    const int*   ei  = (const int*)d_in[1];
    const float* ef  = (const float*)d_in[2];
    const float* ew1 = (const float*)d_in[3];
    const float* eb1 = (const float*)d_in[4];
    const float* ew2 = (const float*)d_in[5];
    const float* eb2 = (const float*)d_in[6];
    const float* nw1 = (const float*)d_in[7];
    const float* nb1 = (const float*)d_in[8];
    const float* nw2 = (const float*)d_in[9];
    const float* nb2 = (const float*)d_in[10];
    const float* eg  = (const float*)d_in[11];
    const float* ebt = (const float*)d_in[12];
    const float* ng  = (const float*)d_in[13];
    const float* nbt = (const float*)d_in[14];

    float* node_out = (float*)d_out;
    float* edge_out = node_out + (size_t)NN * 64;
    char*  ws   = (char*)d_ws;
    float* cnt  = (float*)(ws);             // 50000*4 = 200000 B
    short* ew1t = (short*)(ws + 200704);    // 128*192*2 = 49152 B
    short* ew2t = (short*)(ws + 249856);    // 64*128*2  = 16384 B
    float* agg  = node_out;                 // reuse node_out region as agg accumulator

    hipMemsetAsync(agg, 0, (size_t)NN * 64 * 4, stream);
    hipMemsetAsync(cnt, 0, (size_t)NN * 4, stream);
    prep_e<<<128, 256, 0, stream>>>(ew1, ew2, ew1t, ew2t);
    edge_k<<<NE / 128, 256, 0, stream>>>(nf, ei, ef, ew1t, eb1, ew2t, eb2, eg, ebt,
                                         edge_out, agg, cnt);
    node_valu<<<NN / 4, 256, 0, stream>>>(nf, nw1, nb1, nw2, nb2, ng, nbt,
                                          agg, cnt, node_out);
}

// Round 8
// 654.549 us; speedup vs baseline: 1.9882x; 1.0212x over previous
//
#include <hip/hip_runtime.h>
#include <math.h>

#define NN 50000
#define NE 800000

typedef float f32x4 __attribute__((ext_vector_type(4)));
typedef short s16x8 __attribute__((ext_vector_type(8)));
typedef unsigned int u32;

__device__ __forceinline__ short f2bf(float f) {
    union { float f; u32 u; } v; v.f = f;
    u32 u = v.u;
    u += 0x7FFF + ((u >> 16) & 1);   // round-to-nearest-even
    return (short)(u >> 16);
}

__device__ __forceinline__ s16x8 cvt8(f32x4 a, f32x4 b) {
    s16x8 r;
    r[0] = f2bf(a[0]); r[1] = f2bf(a[1]); r[2] = f2bf(a[2]); r[3] = f2bf(a[3]);
    r[4] = f2bf(b[0]); r[5] = f2bf(b[1]); r[6] = f2bf(b[2]); r[7] = f2bf(b[3]);
    return r;
}

__device__ __forceinline__ float gelu_exact(float x) {
    return 0.5f * x * (1.0f + erff(x * 0.70710678118654752f));
}

// tanh-form GELU: x*sigma(2*0.7978845608*(x+0.044715x^3)); max dev vs erf-GELU
// ~3e-3 on h -> <2e-3 on outputs (margin ~0.07). ~10 VALU ops vs ~25 for erff.
__device__ __forceinline__ float gelu_fast(float x) {
    const float z = 1.5957691216f * x * (1.0f + 0.044715f * x * x);
    return x * __builtin_amdgcn_rcpf(1.0f + __expf(-z));
}

// ---- prep: transpose-convert edge weights to bf16 [col][k] ----
__global__ __launch_bounds__(256) void prep_e(
    const float* __restrict__ ew1, const float* __restrict__ ew2,
    short* __restrict__ ew1t, short* __restrict__ ew2t)
{
    int idx = blockIdx.x * 256 + threadIdx.x;
    if (idx < 24576) {                       // e_w1 [192][128] -> [128][192]
        int k = idx >> 7, c = idx & 127;
        ew1t[c * 192 + k] = f2bf(ew1[idx]);
    } else if (idx < 32768) {                // e_w2 [128][64] -> [64][128]
        int i = idx - 24576; int k = i >> 6, c = i & 63;
        ew2t[c * 128 + k] = f2bf(ew2[i]);
    }
}

// ---- edge kernel: EXACT r6 (certified) except gelu_exact -> gelu_fast ----
// Epilogue stays the SERIAL lane=col form: group-parallel variants failed
// 3x (r2 0.5, r3 1.09, r7 1.125); serial passed 3x (r4, r5, r6). BANNED.
__global__ __launch_bounds__(256) void edge_k(
    const float* __restrict__ nf, const int* __restrict__ ei,
    const float* __restrict__ ef,
    const short* __restrict__ w1t, const float* __restrict__ b1,
    const short* __restrict__ w2t, const float* __restrict__ b2,
    const float* __restrict__ gamma, const float* __restrict__ beta,
    float* __restrict__ eout, float* __restrict__ agg, float* __restrict__ cnt)
{
    __shared__ short h_lds[128][128];        // 32768 B; aliased float[128][64]
    const int tid  = threadIdx.x;
    const int wave = tid >> 6, lane = tid & 63;
    const int lo = lane & 15, hi = lane >> 4;
    const int eb = blockIdx.x * 128 + wave * 32;

    const int ar0 = eb + lo, ar1 = eb + 16 + lo;
    const int s0 = ei[ar0], s1 = ei[ar1];
    const int d0 = ei[NE + ar0], d1 = ei[NE + ar1];

    const float* pS0 = nf + (size_t)s0 * 64;
    const float* pS1 = nf + (size_t)s1 * 64;
    const float* pD0 = nf + (size_t)d0 * 64;
    const float* pD1 = nf + (size_t)d1 * 64;
    const float* pE0 = ef + (size_t)ar0 * 64;
    const float* pE1 = ef + (size_t)ar1 * 64;
    const int o0 = hi * 8, o1 = 32 + hi * 8;

    f32x4 acc[2][8];
#pragma unroll
    for (int i = 0; i < 2; ++i)
#pragma unroll
        for (int j = 0; j < 8; ++j)
#pragma unroll
            for (int q = 0; q < 4; ++q) acc[i][j][q] = 0.0f;

#define KSTEP(PTR0, PTR1, OFF, K0)                                              \
    {                                                                           \
        f32x4 x0l = *(const f32x4*)((PTR0) + (OFF));                            \
        f32x4 x0h = *(const f32x4*)((PTR0) + (OFF) + 4);                        \
        f32x4 x1l = *(const f32x4*)((PTR1) + (OFF));                            \
        f32x4 x1h = *(const f32x4*)((PTR1) + (OFF) + 4);                        \
        s16x8 fa0 = cvt8(x0l, x0h), fa1 = cvt8(x1l, x1h);                       \
        _Pragma("unroll")                                                       \
        for (int ct = 0; ct < 8; ++ct) {                                        \
            s16x8 b = *(const s16x8*)(w1t + (ct * 16 + lo) * 192 + (K0) + hi * 8); \
            acc[0][ct] = __builtin_amdgcn_mfma_f32_16x16x32_bf16(fa0, b, acc[0][ct], 0, 0, 0); \
            acc[1][ct] = __builtin_amdgcn_mfma_f32_16x16x32_bf16(fa1, b, acc[1][ct], 0, 0, 0); \
        }                                                                       \
    }

    KSTEP(pS0, pS1, o0, 0);      // k   0..31 : nf[src] 0..31
    KSTEP(pS0, pS1, o1, 32);     // k  32..63 : nf[src] 32..63
    KSTEP(pD0, pD1, o0, 64);     // k  64..95 : nf[dst] 0..31
    KSTEP(pD0, pD1, o1, 96);     // k  96..127: nf[dst] 32..63
    KSTEP(pE0, pE1, o0, 128);    // k 128..159: ef 0..31
    KSTEP(pE0, pE1, o1, 160);    // k 160..191: ef 32..63
#undef KSTEP

    // bias + tanh GELU -> h_lds (bf16), certified C/D mapping
#pragma unroll
    for (int ct = 0; ct < 8; ++ct) {
        const int col = ct * 16 + lo;
        const float bb = b1[col];
#pragma unroll
        for (int rt = 0; rt < 2; ++rt)
#pragma unroll
            for (int r = 0; r < 4; ++r) {
                float x = acc[rt][ct][r] + bb;
                h_lds[wave * 32 + rt * 16 + hi * 4 + r][col] = f2bf(gelu_fast(x));
            }
    }
    __syncthreads();

    // ---- GEMM2: [128 x 128] @ [128 x 64], MFMA, certified mappings ----
    f32x4 acc2[2][4];
#pragma unroll
    for (int i = 0; i < 2; ++i)
#pragma unroll
        for (int j = 0; j < 4; ++j)
#pragma unroll
            for (int q = 0; q < 4; ++q) acc2[i][j][q] = 0.0f;
#pragma unroll
    for (int ks = 0; ks < 4; ++ks) {
        const int k0 = ks * 32 + hi * 8;
        s16x8 a0 = *(const s16x8*)&h_lds[wave * 32 + lo][k0];
        s16x8 a1 = *(const s16x8*)&h_lds[wave * 32 + 16 + lo][k0];
#pragma unroll
        for (int ct = 0; ct < 4; ++ct) {
            s16x8 b = *(const s16x8*)(w2t + (ct * 16 + lo) * 128 + k0);
            acc2[0][ct] = __builtin_amdgcn_mfma_f32_16x16x32_bf16(a0, b, acc2[0][ct], 0, 0, 0);
            acc2[1][ct] = __builtin_amdgcn_mfma_f32_16x16x32_bf16(a1, b, acc2[1][ct], 0, 0, 0);
        }
    }
    __syncthreads();                          // all h reads done before aliasing overwrite

    // write update u to LDS with the certified C/D mapping (alias h_lds as f32)
    float (*u_lds)[64] = (float (*)[64])h_lds;   // 128*64*4 = 32768 B, exact alias
#pragma unroll
    for (int ct = 0; ct < 4; ++ct)
#pragma unroll
        for (int rt = 0; rt < 2; ++rt)
#pragma unroll
            for (int r = 0; r < 4; ++r)
                u_lds[wave * 32 + rt * 16 + hi * 4 + r][ct * 16 + lo] = acc2[rt][ct][r];
    __syncthreads();

    // ---- certified SERIAL epilogue: lane = output column (0..63) ----
    const float b2v = b2[lane], gmv = gamma[lane], btv = beta[lane];
#pragma unroll 4
    for (int e = 0; e < 32; ++e) {
        const int er   = wave * 32 + e;              // block-local row
        const int erow = blockIdx.x * 128 + er;      // global edge row
        float o = u_lds[er][lane] + b2v + ef[(size_t)erow * 64 + lane];
        float s = o, s2 = o * o;
#pragma unroll
        for (int m = 1; m < 64; m <<= 1) { s += __shfl_xor(s, m); s2 += __shfl_xor(s2, m); }
        const float mean = s * 0.015625f;
        const float var  = s2 * 0.015625f - mean * mean;
        const float rs   = rsqrtf(var + 1e-5f);
        const float out  = (o - mean) * rs * gmv + btv;
        eout[(size_t)erow * 64 + lane] = out;
        const int dn = ei[NE + erow];
        atomicAdd(&agg[(size_t)dn * 64 + lane], out);
        if (lane == 0) atomicAdd(&cnt[dn], 1.0f);
    }
}

// ---- node kernel: simple per-wave f32 VALU (certified — unchanged) ----
__global__ __launch_bounds__(256) void node_valu(
    const float* __restrict__ nf,
    const float* __restrict__ w1, const float* __restrict__ b1,   // [128][128], [128]
    const float* __restrict__ w2, const float* __restrict__ b2,   // [128][64],  [64]
    const float* __restrict__ gamma, const float* __restrict__ beta,
    const float* __restrict__ agg, const float* __restrict__ cnt,
    float* __restrict__ nout)
{
    __shared__ float xs[4][128];
    __shared__ float hs[4][128];
    const int wave = threadIdx.x >> 6, lane = threadIdx.x & 63;
    const int n = blockIdx.x * 4 + wave;         // grid covers exactly NN
    if (n >= NN) return;                          // whole-wave exit; no __syncthreads here

    const float ic = 1.0f / fmaxf(cnt[n], 1.0f);
    xs[wave][lane]      = nf[(size_t)n * 64 + lane];
    xs[wave][64 + lane] = agg[(size_t)n * 64 + lane] * ic;

    float a0 = b1[lane], a1 = b1[64 + lane];
#pragma unroll 8
    for (int k = 0; k < 128; ++k) {
        const float xv = xs[wave][k];            // LDS broadcast
        a0 += xv * w1[k * 128 + lane];
        a1 += xv * w1[k * 128 + 64 + lane];
    }
    hs[wave][lane]      = gelu_exact(a0);
    hs[wave][64 + lane] = gelu_exact(a1);

    float o = b2[lane];
#pragma unroll 8
    for (int k = 0; k < 128; ++k)
        o += hs[wave][k] * w2[k * 64 + lane];
    o += nf[(size_t)n * 64 + lane];              // residual

    float s = o, s2 = o * o;
#pragma unroll
    for (int m = 1; m < 64; m <<= 1) { s += __shfl_xor(s, m); s2 += __shfl_xor(s2, m); }
    const float mean = s * 0.015625f;
    const float var  = s2 * 0.015625f - mean * mean;
    const float rs   = rsqrtf(var + 1e-5f);
    nout[(size_t)n * 64 + lane] = (o - mean) * rs * gamma[lane] + beta[lane];
}

extern "C" void kernel_launch(void* const* d_in, const int* in_sizes, int n_in,
                              void* d_out, int out_size, void* d_ws, size_t ws_size,
                              hipStream_t stream)
{
    const float* nf  = (const float*)d_in[0];
    const int*   ei  = (const int*)d_in[1];
    const float* ef  = (const float*)d_in[2];
    const float* ew1 = (const float*)d_in[3];
    const float* eb1 = (const float*)d_in[4];
    const float* ew2 = (const float*)d_in[5];
    const float* eb2 = (const float*)d_in[6];
    const float* nw1 = (const float*)d_in[7];
    const float* nb1 = (const float*)d_in[8];
    const float* nw2 = (const float*)d_in[9];
    const float* nb2 = (const float*)d_in[10];
    const float* eg  = (const float*)d_in[11];
    const float* ebt = (const float*)d_in[12];
    const float* ng  = (const float*)d_in[13];
    const float* nbt = (const float*)d_in[14];

    float* node_out = (float*)d_out;
    float* edge_out = node_out + (size_t)NN * 64;
    char*  ws   = (char*)d_ws;
    float* cnt  = (float*)(ws);             // 50000*4 = 200000 B
    short* ew1t = (short*)(ws + 200704);    // 128*192*2 = 49152 B
    short* ew2t = (short*)(ws + 249856);    // 64*128*2  = 16384 B
    float* agg  = node_out;                 // reuse node_out region as agg accumulator

    hipMemsetAsync(agg, 0, (size_t)NN * 64 * 4, stream);
    hipMemsetAsync(cnt, 0, (size_t)NN * 4, stream);
    prep_e<<<128, 256, 0, stream>>>(ew1, ew2, ew1t, ew2t);
    edge_k<<<NE / 128, 256, 0, stream>>>(nf, ei, ef, ew1t, eb1, ew2t, eb2, eg, ebt,
                                         edge_out, agg, cnt);
    node_valu<<<NN / 4, 256, 0, stream>>>(nf, nw1, nb1, nw2, nb2, ng, nbt,
                                          agg, cnt, node_out);
}